// Round 1
// baseline (80.737 us; speedup 1.0000x reference)
//
#include <hip/hip_runtime.h>

// Problem constants (from reference): 5 wires, 100000 gates, batch 64.
#define N_WIRES 5
#define BATCH 64

// Kernel A geometry: 64 blocks x 256 threads = 16384 lanes, each owning a
// contiguous chunk of the gate sequence (order matters - matrix product).
#define BLOCKS_A 64
#define THREADS_A 256
#define LANES (BLOCKS_A * THREADS_A)
#define TUP (N_WIRES * 8)   // 5 wires x 2x2 complex = 40 floats per tuple

// Complex 2x2 layout: [00r,00i,01r,01i,10r,10i,11r,11i]
// R = B * A (B = later gates, multiplies on the LEFT)
__device__ __forceinline__ void cmatmul(float* r, const float* B, const float* A) {
    r[0] = B[0]*A[0] - B[1]*A[1] + B[2]*A[4] - B[3]*A[5];
    r[1] = B[0]*A[1] + B[1]*A[0] + B[2]*A[5] + B[3]*A[4];
    r[2] = B[0]*A[2] - B[1]*A[3] + B[2]*A[6] - B[3]*A[7];
    r[3] = B[0]*A[3] + B[1]*A[2] + B[2]*A[7] + B[3]*A[6];
    r[4] = B[4]*A[0] - B[5]*A[1] + B[6]*A[4] - B[7]*A[5];
    r[5] = B[4]*A[1] + B[5]*A[0] + B[6]*A[5] + B[7]*A[4];
    r[6] = B[4]*A[2] - B[5]*A[3] + B[6]*A[6] - B[7]*A[7];
    r[7] = B[4]*A[3] + B[5]*A[2] + B[6]*A[7] + B[7]*A[6];
}

// Kernel A: per-lane ordered partial products of the gate stream, restricted
// per wire; order-preserving adjacent-pair tree reduction within the block.
__global__ __launch_bounds__(THREADS_A)
void gate_partials(const float* __restrict__ angles,
                   const int*   __restrict__ wires,
                   const int*   __restrict__ types,
                   int n_ops, int chunk,
                   float* __restrict__ ws)
{
    const int lane = blockIdx.x * THREADS_A + threadIdx.x;

    // 5 per-wire accumulators, init to identity
    float acc[N_WIRES][8];
    #pragma unroll
    for (int w = 0; w < N_WIRES; ++w) {
        acc[w][0] = 1.f; acc[w][1] = 0.f; acc[w][2] = 0.f; acc[w][3] = 0.f;
        acc[w][4] = 0.f; acc[w][5] = 0.f; acc[w][6] = 1.f; acc[w][7] = 0.f;
    }

    const int g0 = lane * chunk;
    const int g1 = min(g0 + chunk, n_ops);
    for (int g = g0; g < g1; ++g) {
        const float ang = angles[g];
        const int   w   = wires[g];
        const int   t   = types[g];
        float s, c;
        __sincosf(0.5f * ang, &s, &c);
        // U = exp(-i*theta/2 * n.sigma) = [[c+i*na, nb+i*ng], [-nb+i*ng, c-i*na]]
        // RX (t==0): ng=-s ; RY (t==1): nb=-s ; RZ (t==2): na=-s
        const float na = (t == 2) ? -s : 0.f;
        const float nb = (t == 1) ? -s : 0.f;
        const float ng = (t == 0) ? -s : 0.f;
        #pragma unroll
        for (int k = 0; k < N_WIRES; ++k) {
            if (w == k) {
                float* m = acc[k];
                const float m00r =  c*m[0] - na*m[1] + nb*m[4] - ng*m[5];
                const float m00i =  c*m[1] + na*m[0] + nb*m[5] + ng*m[4];
                const float m01r =  c*m[2] - na*m[3] + nb*m[6] - ng*m[7];
                const float m01i =  c*m[3] + na*m[2] + nb*m[7] + ng*m[6];
                const float m10r = -nb*m[0] - ng*m[1] + c*m[4] + na*m[5];
                const float m10i = -nb*m[1] + ng*m[0] + c*m[5] - na*m[4];
                const float m11r = -nb*m[2] - ng*m[3] + c*m[6] + na*m[7];
                const float m11i = -nb*m[3] + ng*m[2] + c*m[7] - na*m[6];
                m[0]=m00r; m[1]=m00i; m[2]=m01r; m[3]=m01i;
                m[4]=m10r; m[5]=m10i; m[6]=m11r; m[7]=m11i;
            }
        }
    }

    // Order-preserving block reduction. lds[t] covers gates [t*chunk,(t+1)*chunk);
    // adjacent pairing keeps ranges contiguous: T[t] = T[t+st] * T[t] (later on left).
    __shared__ float lds[THREADS_A][TUP];   // 256*40*4 = 40 KB
    #pragma unroll
    for (int i = 0; i < TUP; ++i) lds[threadIdx.x][i] = acc[i >> 3][i & 7];
    __syncthreads();
    for (int st = 1; st < THREADS_A; st <<= 1) {
        if ((threadIdx.x & (2*st - 1)) == 0) {
            #pragma unroll
            for (int w = 0; w < N_WIRES; ++w) {
                float r[8];
                cmatmul(r, &lds[threadIdx.x + st][w*8], &lds[threadIdx.x][w*8]);
                #pragma unroll
                for (int i = 0; i < 8; ++i) lds[threadIdx.x][w*8 + i] = r[i];
            }
        }
        __syncthreads();
    }
    if (threadIdx.x == 0) {
        #pragma unroll
        for (int i = 0; i < TUP; ++i) ws[blockIdx.x * TUP + i] = lds[0][i];
    }
}

// Kernel B: reduce the 64 block partials (ordered), then compute the 320
// outputs: out[b,k] = 2*Im(conj(v0)*v1), v = U_k * [cos(x/2), -i sin(x/2)]^T
__global__ __launch_bounds__(320)
void finalize(const float* __restrict__ x,
              const float* __restrict__ ws,
              float* __restrict__ out)
{
    __shared__ float red[BLOCKS_A][TUP];
    const int tid = threadIdx.x;
    if (tid < BLOCKS_A) {
        #pragma unroll
        for (int i = 0; i < TUP; ++i) red[tid][i] = ws[tid * TUP + i];
    }
    __syncthreads();
    for (int st = 1; st < BLOCKS_A; st <<= 1) {
        if (tid < BLOCKS_A && (tid & (2*st - 1)) == 0) {
            #pragma unroll
            for (int w = 0; w < N_WIRES; ++w) {
                float r[8];
                cmatmul(r, &red[tid + st][w*8], &red[tid][w*8]);
                #pragma unroll
                for (int i = 0; i < 8; ++i) red[tid][w*8 + i] = r[i];
            }
        }
        __syncthreads();
    }

    if (tid < BATCH * N_WIRES) {
        const int b = tid / N_WIRES;
        const int k = tid % N_WIRES;
        const float xv = x[b * N_WIRES + k];
        float sx, cx;
        __sincosf(0.5f * xv, &sx, &cx);
        const float* U = &red[0][k*8];
        // v0 = cx*U00 - i*sx*U01 ; v1 = cx*U10 - i*sx*U11
        const float v0r = cx*U[0] + sx*U[3];
        const float v0i = cx*U[1] - sx*U[2];
        const float v1r = cx*U[4] + sx*U[7];
        const float v1i = cx*U[5] - sx*U[6];
        out[tid] = 2.f * (v0r * v1i - v0i * v1r);
    }
}

extern "C" void kernel_launch(void* const* d_in, const int* in_sizes, int n_in,
                              void* d_out, int out_size, void* d_ws, size_t ws_size,
                              hipStream_t stream) {
    const float* x      = (const float*)d_in[0];
    const float* angles = (const float*)d_in[1];
    const int*   wires  = (const int*)d_in[2];
    const int*   types  = (const int*)d_in[3];
    float* out = (float*)d_out;
    float* ws  = (float*)d_ws;   // needs BLOCKS_A*TUP*4 = 10240 bytes

    const int n_ops = in_sizes[1];
    const int chunk = (n_ops + LANES - 1) / LANES;

    gate_partials<<<BLOCKS_A, THREADS_A, 0, stream>>>(angles, wires, types, n_ops, chunk, ws);
    finalize<<<1, 320, 0, stream>>>(x, ws, out);
}

// Round 2
// 67.368 us; speedup vs baseline: 1.1985x; 1.1985x over previous
//
#include <hip/hip_runtime.h>

// Problem: 5-wire quantum circuit, 100000 single-qubit rotations, batch 64.
// All gates are single-qubit -> circuit factorizes per wire into an ordered
// SU(2) product. SU(2) == unit quaternions: R_n(theta) <-> (cos t/2, sin t/2 * n).
// Gate update = signed permutation + 4 FMAs. Final <Y_k> from the per-wire
// quaternion and the initial RX(x) product state.

#define N_WIRES 5
#define BATCH 64
#define BLOCKS_A 64
#define THREADS_A 256
#define LANES (BLOCKS_A * THREADS_A)
#define QTUP (N_WIRES * 4)   // 5 quaternions = 20 floats

// r = b (x) a   (b = later gates, multiplies on the LEFT)
__device__ __forceinline__ void qmul(float* r, const float* b, const float* a) {
    r[0] = b[0]*a[0] - b[1]*a[1] - b[2]*a[2] - b[3]*a[3];
    r[1] = b[0]*a[1] + b[1]*a[0] + b[2]*a[3] - b[3]*a[2];
    r[2] = b[0]*a[2] - b[1]*a[3] + b[2]*a[0] + b[3]*a[1];
    r[3] = b[0]*a[3] + b[1]*a[2] - b[2]*a[1] + b[3]*a[0];
}

// Order-preserving adjacent-pair scan across one wave.
// After step s, lane t holds the product of chunks [t, t+2^s); lane 0 exact.
__device__ __forceinline__ void wave_reduce6(float* t) {
    for (int st = 1; st < 64; st <<= 1) {
        float o[QTUP];
        #pragma unroll
        for (int i = 0; i < QTUP; ++i) o[i] = __shfl_down(t[i], st, 64);
        #pragma unroll
        for (int w = 0; w < N_WIRES; ++w) {
            float r[4];
            qmul(r, &o[4*w], &t[4*w]);
            t[4*w+0] = r[0]; t[4*w+1] = r[1]; t[4*w+2] = r[2]; t[4*w+3] = r[3];
        }
    }
}

__global__ __launch_bounds__(THREADS_A)
void gate_partials(const float* __restrict__ angles,
                   const int*   __restrict__ wires,
                   const int*   __restrict__ types,
                   int n_ops, int chunk,
                   float* __restrict__ ws)
{
    const int lane = blockIdx.x * THREADS_A + threadIdx.x;

    // 5 per-wire quaternion accumulators, init identity (1,0,0,0)
    float acc[N_WIRES][4];
    #pragma unroll
    for (int w = 0; w < N_WIRES; ++w) {
        acc[w][0] = 1.f; acc[w][1] = 0.f; acc[w][2] = 0.f; acc[w][3] = 0.f;
    }

    const int g0 = lane * chunk;
    const int g1 = min(g0 + chunk, n_ops);
    for (int g = g0; g < g1; ++g) {
        const float ang = angles[g];
        const int   w   = wires[g];
        const int   t   = types[g];
        float s, c;
        __sincosf(0.5f * ang, &s, &c);

        // branchless gather acc[w] -> q
        float qw = acc[0][0], qx = acc[0][1], qy = acc[0][2], qz = acc[0][3];
        #pragma unroll
        for (int k = 1; k < N_WIRES; ++k) {
            const bool m = (w == k);
            qw = m ? acc[k][0] : qw;  qx = m ? acc[k][1] : qx;
            qy = m ? acc[k][2] : qy;  qz = m ? acc[k][3] : qz;
        }
        // p = e_t (x) q, signed permutation:
        //   i(x)q = (-x, w, -z,  y) ; j(x)q = (-y, z, w, -x) ; k(x)q = (-z, -y, x, w)
        const float pw = (t == 0) ? -qx : (t == 1) ? -qy : -qz;
        const float px = (t == 0) ?  qw : (t == 1) ?  qz : -qy;
        const float py = (t == 0) ? -qz : (t == 1) ?  qw :  qx;
        const float pz = (t == 0) ?  qy : (t == 1) ? -qx :  qw;
        // q' = (c + s*e_t) (x) q
        const float nw = c*qw + s*pw;
        const float nx = c*qx + s*px;
        const float ny = c*qy + s*py;
        const float nz = c*qz + s*pz;
        // branchless scatter back
        #pragma unroll
        for (int k = 0; k < N_WIRES; ++k) {
            const bool m = (w == k);
            acc[k][0] = m ? nw : acc[k][0];  acc[k][1] = m ? nx : acc[k][1];
            acc[k][2] = m ? ny : acc[k][2];  acc[k][3] = m ? nz : acc[k][3];
        }
    }

    // intra-wave ordered reduction
    float t[QTUP];
    #pragma unroll
    for (int i = 0; i < QTUP; ++i) t[i] = acc[i >> 2][i & 3];
    wave_reduce6(t);

    // cross-wave (4 waves) via tiny LDS, thread 0 combines in order
    __shared__ float lds[4][QTUP];
    const int wave = threadIdx.x >> 6;
    if ((threadIdx.x & 63) == 0) {
        #pragma unroll
        for (int i = 0; i < QTUP; ++i) lds[wave][i] = t[i];
    }
    __syncthreads();
    if (threadIdx.x == 0) {
        float r[QTUP];
        #pragma unroll
        for (int i = 0; i < QTUP; ++i) r[i] = lds[0][i];
        #pragma unroll
        for (int v = 1; v < 4; ++v) {
            #pragma unroll
            for (int w = 0; w < N_WIRES; ++w) {
                float z[4];
                qmul(z, &lds[v][4*w], &r[4*w]);
                r[4*w+0] = z[0]; r[4*w+1] = z[1]; r[4*w+2] = z[2]; r[4*w+3] = z[3];
            }
        }
        #pragma unroll
        for (int i = 0; i < QTUP; ++i) ws[blockIdx.x * QTUP + i] = r[i];
    }
}

// Reduce 64 block partials (ordered, one wave), then all 320 outputs.
// U from quaternion (w,x,y,z): U00=(w,-z) U01=(-y,-x) U10=(y,-x) U11=(w,z)
// v = U * [cos(x/2), -i sin(x/2)]^T ; out = 2*Im(conj(v0) v1)
__global__ __launch_bounds__(320)
void finalize(const float* __restrict__ x,
              const float* __restrict__ ws,
              float* __restrict__ out)
{
    __shared__ float U[QTUP];
    const int tid = threadIdx.x;
    if (tid < 64) {
        float t[QTUP];
        #pragma unroll
        for (int i = 0; i < QTUP; ++i) t[i] = ws[tid * QTUP + i];
        wave_reduce6(t);
        if (tid == 0) {
            #pragma unroll
            for (int i = 0; i < QTUP; ++i) U[i] = t[i];
        }
    }
    __syncthreads();

    if (tid < BATCH * N_WIRES) {
        const int b = tid / N_WIRES;
        const int k = tid % N_WIRES;
        const float xv = x[b * N_WIRES + k];
        float sx, cx;
        __sincosf(0.5f * xv, &sx, &cx);
        const float* q = &U[4*k];
        const float v0r =  cx*q[0] - sx*q[1];
        const float v0i = -cx*q[3] + sx*q[2];
        const float v1r =  cx*q[2] + sx*q[3];
        const float v1i = -cx*q[1] - sx*q[0];
        out[tid] = 2.f * (v0r * v1i - v0i * v1r);
    }
}

extern "C" void kernel_launch(void* const* d_in, const int* in_sizes, int n_in,
                              void* d_out, int out_size, void* d_ws, size_t ws_size,
                              hipStream_t stream) {
    const float* x      = (const float*)d_in[0];
    const float* angles = (const float*)d_in[1];
    const int*   wires  = (const int*)d_in[2];
    const int*   types  = (const int*)d_in[3];
    float* out = (float*)d_out;
    float* ws  = (float*)d_ws;   // uses BLOCKS_A*QTUP*4 = 5120 bytes

    const int n_ops = in_sizes[1];
    const int chunk = (n_ops + LANES - 1) / LANES;

    gate_partials<<<BLOCKS_A, THREADS_A, 0, stream>>>(angles, wires, types, n_ops, chunk, ws);
    finalize<<<1, 320, 0, stream>>>(x, ws, out);
}